// Round 10
// baseline (90.987 us; speedup 1.0000x reference)
//
#include <hip/hip_runtime.h>
#include <math.h>

#define HDIM 128
#define WDIM 128
#define CDIM 64
#define BDIM 4

#define TILE_W 16
#define TILE_H 8
#define HALO_W 20
#define HALO_H 12
#define NHALO (HALO_W * HALO_H)   // 240 halo px = 15 M-tiles of 16
#define PSTRIDE 68                // cm/crs pixel stride (16B-aligned, 4 mod 32)
#define WSTRIDE 65                // W LDS stride (2-way banks on frag reads)

typedef short bf16x8 __attribute__((ext_vector_type(8)));
typedef float f32x4  __attribute__((ext_vector_type(4)));

// exact fp32 -> bf16 hi/lo split (3-product emulation, |err| ~ 2^-14)
__device__ __forceinline__ void split_bf16(float f, short& hi, short& lo) {
    unsigned u = __float_as_uint(f);
    hi = (short)(u >> 16);
    float hf = __uint_as_float(u & 0xffff0000u);
    float l  = f - hf;
    lo = (short)(__float_as_uint(l) >> 16);
}

__device__ __forceinline__ void build_A(const float4 p0, const float4 p1,
                                        const float4 p2, const float4 p3,
                                        bf16x8 Ahi[2], bf16x8 Alo[2]) {
    float fv[16] = {p0.x,p0.y,p0.z,p0.w, p1.x,p1.y,p1.z,p1.w,
                    p2.x,p2.y,p2.z,p2.w, p3.x,p3.y,p3.z,p3.w};
    #pragma unroll
    for (int ks = 0; ks < 2; ++ks)
        #pragma unroll
        for (int j = 0; j < 8; ++j) {
            short hi, lo; split_bf16(fv[8 * ks + j], hi, lo);
            Ahi[ks][j] = hi; Alo[ks][j] = lo;
        }
}

// ---------------------------------------------------------------------------
// Fused MFMA local-attn, round-10: ALL global loads hoisted to kernel top.
//   Round-9 post-mortem: kernel was ~34 us vs ~15 predicted — 4 serialized
//   cold-HBM episodes (268 MB harness fill evicts L2/L3 every iter) exposed
//   ~900-cyc latency per episode at 2 blocks/CU with barrier-phased waves.
//   Now Wm/Wr raw (16+16 dw), xm A (8 f4), xr halo tiles 0-1 (8 f4) issue
//   up-front in one overlapped episode; xr tiles 2-3 issue at phase-4 entry
//   (covered by tiles 0-1 compute). __launch_bounds__(256,2) pins VGPR<=256
//   (2 waves/SIMD — matches the 2-blocks/CU LDS cap).
//   LDS multiplex (65,280 B): Wsh[0..4160) | cms[4352..13056) | crs[0..16320).
// ---------------------------------------------------------------------------
__global__ __launch_bounds__(256, 2)
void fused_mfma_local_attn(const float* __restrict__ xm,
                           const float* __restrict__ xr,
                           const float* __restrict__ Wm,
                           const float* __restrict__ Wr,
                           float* __restrict__ out) {
    __shared__ float lds[16320];        // 65,280 B
    float* Wsh = lds;                   // [64][65]
    float* cms = lds + 4352;            // [128][68]
    float* crs = lds;                   // [240][68]

    const int t    = threadIdx.x;
    const int lane = t & 63;
    const int wv   = t >> 6;
    const int m    = lane & 15;
    const int quad = lane >> 4;
    const int tx0  = blockIdx.x * TILE_W;
    const int ty0  = blockIdx.y * TILE_H;
    const int b    = blockIdx.z;

    // ============ prefetch EVERYTHING (one HBM latency episode) ============
    float wmv[16], wrv[16];
    #pragma unroll
    for (int i = 0; i < 16; ++i) wmv[i] = Wm[t + 256 * i];
    #pragma unroll
    for (int i = 0; i < 16; ++i) wrv[i] = Wr[t + 256 * i];

    float4 am[2][4];                    // xm A raw: 2 M-tiles per wave
    #pragma unroll
    for (int s = 0; s < 2; ++s) {
        const int tile = 2 * wv + s;
        const float* ap = xm + (((size_t)b * HDIM + ty0 + tile) * WDIM
                                + tx0 + m) * CDIM + quad * 8;
        am[s][0] = *(const float4*)(ap);
        am[s][1] = *(const float4*)(ap + 4);
        am[s][2] = *(const float4*)(ap + 32);
        am[s][3] = *(const float4*)(ap + 36);
    }

    float4 ar[2][4];                    // xr halo raw: tiles tj = wv, wv+4
    #pragma unroll
    for (int s = 0; s < 2; ++s) {
        const int tj = wv + 4 * s;
        const int hp = tj * 16 + m;
        const int hy = hp / HALO_W;
        const int hx = hp - hy * HALO_W;
        const int gy = ty0 + hy - 2, gx = tx0 + hx - 2;
        float4 z = make_float4(0.f, 0.f, 0.f, 0.f);
        ar[s][0] = z; ar[s][1] = z; ar[s][2] = z; ar[s][3] = z;
        if (gy >= 0 && gy < HDIM && gx >= 0 && gx < WDIM) {
            const float* ap = xr + (((size_t)b * HDIM + gy) * WDIM + gx) * CDIM
                              + quad * 8;
            ar[s][0] = *(const float4*)(ap);
            ar[s][1] = *(const float4*)(ap + 4);
            ar[s][2] = *(const float4*)(ap + 32);
            ar[s][3] = *(const float4*)(ap + 36);
        }
    }

    // ============ phase 1: stage Wm ============
    #pragma unroll
    for (int i = 0; i < 16; ++i) {
        int L = t + 256 * i;
        Wsh[(L >> 6) * WSTRIDE + (L & 63)] = wmv[i];
    }
    __syncthreads();                    // B1

    bf16x8 Bhi[2][4], Blo[2][4];
    #pragma unroll
    for (int ks = 0; ks < 2; ++ks)
        #pragma unroll
        for (int nt = 0; nt < 4; ++nt)
            #pragma unroll
            for (int j = 0; j < 8; ++j) {
                float f = Wsh[(ks * 32 + quad * 8 + j) * WSTRIDE + nt * 16 + m];
                short hi, lo; split_bf16(f, hi, lo);
                Bhi[ks][nt][j] = hi; Blo[ks][nt][j] = lo;
            }

    // ============ phase 2: cm GEMM ============
    #pragma unroll
    for (int s = 0; s < 2; ++s) {
        const int tile = 2 * wv + s;
        bf16x8 Ahi[2], Alo[2];
        build_A(am[s][0], am[s][1], am[s][2], am[s][3], Ahi, Alo);
        f32x4 acc[4];
        #pragma unroll
        for (int nt = 0; nt < 4; ++nt)
            { acc[nt][0]=0.f; acc[nt][1]=0.f; acc[nt][2]=0.f; acc[nt][3]=0.f; }
        #pragma unroll
        for (int ks = 0; ks < 2; ++ks)
            #pragma unroll
            for (int nt = 0; nt < 4; ++nt) {
                acc[nt] = __builtin_amdgcn_mfma_f32_16x16x32_bf16(Ahi[ks], Bhi[ks][nt], acc[nt], 0,0,0);
                acc[nt] = __builtin_amdgcn_mfma_f32_16x16x32_bf16(Ahi[ks], Blo[ks][nt], acc[nt], 0,0,0);
                acc[nt] = __builtin_amdgcn_mfma_f32_16x16x32_bf16(Alo[ks], Bhi[ks][nt], acc[nt], 0,0,0);
            }
        #pragma unroll
        for (int nt = 0; nt < 4; ++nt)
            #pragma unroll
            for (int r = 0; r < 4; ++r)
                cms[(tile * 16 + quad * 4 + r) * PSTRIDE + nt * 16 + m] = acc[nt][r];
    }
    __syncthreads();                    // B2: Wsh(Wm) reads + cms writes done

    // ============ phase 3: stage Wr, build Br, extract qv ============
    #pragma unroll
    for (int i = 0; i < 16; ++i) {
        int L = t + 256 * i;
        Wsh[(L >> 6) * WSTRIDE + (L & 63)] = wrv[i];
    }
    __syncthreads();                    // B3

    #pragma unroll
    for (int ks = 0; ks < 2; ++ks)
        #pragma unroll
        for (int nt = 0; nt < 4; ++nt)
            #pragma unroll
            for (int j = 0; j < 8; ++j) {
                float f = Wsh[(ks * 32 + quad * 8 + j) * WSTRIDE + nt * 16 + m];
                short hi, lo; split_bf16(f, hi, lo);
                Bhi[ks][nt][j] = hi; Blo[ks][nt][j] = lo;
            }

    const int pl = t >> 1;
    const int cg = t & 1;
    float4 qv[8];
    #pragma unroll
    for (int mq = 0; mq < 8; ++mq)
        qv[mq] = *(const float4*)&cms[pl * PSTRIDE + cg * 32 + 4 * mq];
    __syncthreads();                    // B4: Wsh/cms reads done before crs

    // ============ phase 4: cr halo GEMM (15 M-tiles over 4 waves) ============
    // issue tiles 2-3 loads FIRST (latency covered by tiles 0-1 compute)
    float4 ar2[2][4];
    #pragma unroll
    for (int s = 0; s < 2; ++s) {
        const int tj = wv + 4 * (s + 2);
        float4 z = make_float4(0.f, 0.f, 0.f, 0.f);
        ar2[s][0] = z; ar2[s][1] = z; ar2[s][2] = z; ar2[s][3] = z;
        if (tj < 15) {
            const int hp = tj * 16 + m;
            const int hy = hp / HALO_W;
            const int hx = hp - hy * HALO_W;
            const int gy = ty0 + hy - 2, gx = tx0 + hx - 2;
            if (gy >= 0 && gy < HDIM && gx >= 0 && gx < WDIM) {
                const float* ap = xr + (((size_t)b * HDIM + gy) * WDIM + gx) * CDIM
                                  + quad * 8;
                ar2[s][0] = *(const float4*)(ap);
                ar2[s][1] = *(const float4*)(ap + 4);
                ar2[s][2] = *(const float4*)(ap + 32);
                ar2[s][3] = *(const float4*)(ap + 36);
            }
        }
    }

    #pragma unroll
    for (int s = 0; s < 4; ++s) {
        const int tj = wv + 4 * s;
        if (tj < 15) {
            const float4* pa = (s < 2) ? ar[s] : ar2[s - 2];
            bf16x8 Ahi[2], Alo[2];
            build_A(pa[0], pa[1], pa[2], pa[3], Ahi, Alo);
            f32x4 acc[4];
            #pragma unroll
            for (int nt = 0; nt < 4; ++nt)
                { acc[nt][0]=0.f; acc[nt][1]=0.f; acc[nt][2]=0.f; acc[nt][3]=0.f; }
            #pragma unroll
            for (int ks = 0; ks < 2; ++ks)
                #pragma unroll
                for (int nt = 0; nt < 4; ++nt) {
                    acc[nt] = __builtin_amdgcn_mfma_f32_16x16x32_bf16(Ahi[ks], Bhi[ks][nt], acc[nt], 0,0,0);
                    acc[nt] = __builtin_amdgcn_mfma_f32_16x16x32_bf16(Ahi[ks], Blo[ks][nt], acc[nt], 0,0,0);
                    acc[nt] = __builtin_amdgcn_mfma_f32_16x16x32_bf16(Alo[ks], Bhi[ks][nt], acc[nt], 0,0,0);
                }
            #pragma unroll
            for (int nt = 0; nt < 4; ++nt)
                #pragma unroll
                for (int r = 0; r < 4; ++r)
                    crs[(tj * 16 + quad * 4 + r) * PSTRIDE + nt * 16 + m] = acc[nt][r];
        }
    }
    __syncthreads();                    // B5

    // ============ phase 5: scores + softmax (proven) ============
    const int lx = pl & (TILE_W - 1);
    const int ly = pl >> 4;
    const size_t gpx = ((size_t)b * HDIM + ty0 + ly) * WDIM + tx0 + lx;

    float s[26];
    #pragma unroll
    for (int k = 0; k < 25; ++k) {
        const int i = k / 5, j = k % 5;
        const int p = (ly + i) * HALO_W + (lx + j);
        const float4* kp = (const float4*)&crs[p * PSTRIDE + cg * 32];
        float acc = 0.f;
        #pragma unroll
        for (int mq = 0; mq < 8; ++mq) {
            float4 v = kp[mq];
            acc = fmaf(qv[mq].x, v.x, acc);
            acc = fmaf(qv[mq].y, v.y, acc);
            acc = fmaf(qv[mq].z, v.z, acc);
            acc = fmaf(qv[mq].w, v.w, acc);
        }
        s[k] = acc;
    }
    {
        float acc = 0.f;
        #pragma unroll
        for (int mq = 0; mq < 8; ++mq) {
            float4 v = qv[mq];
            acc = fmaf(v.x, v.x, acc);
            acc = fmaf(v.y, v.y, acc);
            acc = fmaf(v.z, v.z, acc);
            acc = fmaf(v.w, v.w, acc);
        }
        s[25] = acc;
    }

    #pragma unroll
    for (int k = 0; k < 26; ++k) s[k] += __shfl_xor(s[k], 1);

    float mx = s[0];
    #pragma unroll
    for (int k = 1; k < 26; ++k) mx = fmaxf(mx, s[k]);
    float sum = 0.f;
    #pragma unroll
    for (int k = 0; k < 26; ++k) { s[k] = __expf(s[k] - mx); sum += s[k]; }
    const float inv = 1.f / sum;

    float* op = &out[gpx * 26 + cg * 13];
    if (cg == 0) {
        #pragma unroll
        for (int k = 0; k < 13; ++k) op[k] = s[k] * inv;
    } else {
        #pragma unroll
        for (int k = 0; k < 13; ++k) op[k] = s[13 + k] * inv;
    }
}

// ---------------------------------------------------------------------------
extern "C" void kernel_launch(void* const* d_in, const int* in_sizes, int n_in,
                              void* d_out, int out_size, void* d_ws, size_t ws_size,
                              hipStream_t stream) {
    const float* xm = (const float*)d_in[0];
    const float* xr = (const float*)d_in[1];
    const float* Wm = (const float*)d_in[2];
    const float* Wr = (const float*)d_in[3];
    float* outp = (float*)d_out;

    dim3 g(WDIM / TILE_W, HDIM / TILE_H, BDIM);   // 8 x 16 x 4 = 512 blocks
    fused_mfma_local_attn<<<g, 256, 0, stream>>>(xm, xr, Wm, Wr, outp);
}